// Round 6
// baseline (473.451 us; speedup 1.0000x reference)
//
#include <hip/hip_runtime.h>

typedef short bf16x8 __attribute__((ext_vector_type(8)));
typedef float f32x4 __attribute__((ext_vector_type(4)));

#define HID   2048
#define S_LEN 2048
#define NH    16
#define HD    128
#define BATCH 2
#define NROWS (BATCH * S_LEN)  // 4096

__device__ __forceinline__ float bf2f(unsigned short u) {
    union { unsigned int i; float f; } v;
    v.i = ((unsigned int)u) << 16;
    return v.f;
}
__device__ __forceinline__ unsigned short f2bf(float f) {
    union { float f; unsigned int i; } v;
    v.f = f;
    unsigned int u = v.i;
    return (unsigned short)((u + 0x7fffu + ((u >> 16) & 1u)) >> 16);
}

// packed f32x2 -> bf16x2 (RNE). Prefer HW v_cvt_pk_bf16_f32 on gfx950.
__device__ __forceinline__ unsigned int pkbf(float a, float b) {
#if defined(__has_builtin) && __has_builtin(__builtin_amdgcn_cvt_pk_bf16_f32)
    typedef __bf16 bf2_t __attribute__((ext_vector_type(2)));
    bf2_t v = __builtin_amdgcn_cvt_pk_bf16_f32(a, b);
    unsigned int u;
    __builtin_memcpy(&u, &v, 4);
    return u;
#else
    return (unsigned int)f2bf(a) | ((unsigned int)f2bf(b) << 16);
#endif
}

__device__ __forceinline__ float exp2_fast(float x) {
#if defined(__has_builtin) && __has_builtin(__builtin_amdgcn_exp2f)
    return __builtin_amdgcn_exp2f(x);
#else
    return __expf(x * 0.6931471805599453f);
#endif
}

// async global->LDS, 16B per lane. LDS dest = wave-uniform base + lane*16B.
__device__ __forceinline__ void async16(const unsigned short* g, unsigned short* l) {
    __builtin_amdgcn_global_load_lds(
        (const __attribute__((address_space(1))) unsigned int*)g,
        (__attribute__((address_space(3))) unsigned int*)l, 16, 0, 0);
}

// ---------------- prep: z<3 -> transpose+cast W_z; z==3 -> cast hs -> bf16 ----------------
__global__ __launch_bounds__(256) void prep(const float* __restrict__ hs,
                                            const float* __restrict__ Wa,
                                            const float* __restrict__ Wb,
                                            const float* __restrict__ Wc,
                                            unsigned short* __restrict__ Xb,
                                            unsigned short* __restrict__ WT) {
    int z = blockIdx.z;
    int t = threadIdx.x;
    if (z == 3) {
        size_t idx = (((size_t)blockIdx.y * 64 + blockIdx.x) * 256 + t) * 8;
        float4 v0 = *(const float4*)(hs + idx);
        float4 v1 = *(const float4*)(hs + idx + 4);
        uint4 o;
        o.x = pkbf(v0.x, v0.y);
        o.y = pkbf(v0.z, v0.w);
        o.z = pkbf(v1.x, v1.y);
        o.w = pkbf(v1.z, v1.w);
        *(uint4*)(Xb + idx) = o;
        return;
    }
    __shared__ float tile[32][33];
    int tx = t & 31, ty = t >> 5;  // 32 x 8
    int bx = blockIdx.x, by = blockIdx.y;
    const float* W = (z == 0) ? Wa : ((z == 1) ? Wb : Wc);
    unsigned short* dst = WT + (size_t)z * HID * HID;
#pragma unroll
    for (int i = 0; i < 4; i++)
        tile[ty + i * 8][tx] = W[(size_t)(by * 32 + ty + i * 8) * HID + bx * 32 + tx];
    __syncthreads();
#pragma unroll
    for (int i = 0; i < 4; i++)
        dst[(size_t)(bx * 32 + ty + i * 8) * HID + by * 32 + tx] = f2bf(tile[tx][ty + i * 8]);
}

// ---------------- standalone transpose + cast (used for Wo) ----------------
__global__ __launch_bounds__(256) void transpose_cast(const float* __restrict__ W,
                                                      unsigned short* __restrict__ WT) {
    __shared__ float tile[32][33];
    int t = threadIdx.x;
    int tx = t & 31, ty = t >> 5;
    int bx = blockIdx.x, by = blockIdx.y;
#pragma unroll
    for (int i = 0; i < 4; i++)
        tile[ty + i * 8][tx] = W[(size_t)(by * 32 + ty + i * 8) * HID + bx * 32 + tx];
    __syncthreads();
#pragma unroll
    for (int i = 0; i < 4; i++)
        WT[(size_t)(bx * 32 + ty + i * 8) * HID + by * 32 + tx] = f2bf(tile[tx][ty + i * 8]);
}

// ===========================================================================
// QKV GEMM — 256^2 4-phase template (T2+T3+T4+T5), fused RoPE/V^T.
//
// Tile 256x256, BK=64, 8 waves (2M x 4N), wave output 128x64.
// LDS 128 KB: 2 dbuf x (A[256][64] + B[256][64]) bf16, 128B rows.
// Swizzle (proven 0-conflict in gemm_bt): store 16B-chunk p of row r holds
// global chunk p ^ (r&7)  [linear DMA dest, pre-swizzled source — rule 21];
// read frag (row, k-chunk kk*4+quad) at chunk (kk*4+quad) ^ (c&7).
//
// Per K-tile kt (32 total), 4 phases; phase p in 1..4:
//   ds_read: p==1: all 8 B-frags (held in reg all 4 phases) + A mt0,1
//            p>1 : A frags mt=2(p-1), 2(p-1)+1           [4 x b128]
//   stage one half-tile of kt+1 (2 block-loads = 2 async16/wave):
//            p1: B J0,J1   p2: B J2,J3   p3: A J0,J2   p4: A J1,J3
//   s_barrier; setprio(1); 16 MFMA; setprio(0); s_barrier
//
// vmcnt ledger (r5 POST-MORTEM FIX — the r5 vmcnt(6) raced):
//   next ph1 reads B0-B3 + A J0/J2  => at p4 publish, only A J1,J3 (the 2
//     newest issues) may remain in flight  => vmcnt(2) at phase 4.
//   ph3/ph4 read A J1/J3 (staged at prev p4) => drain by end of phase 2:
//     outstanding there = {A1,A3 old} + {B0'..B3'} = 6 => vmcnt(4) drains
//     exactly the 2 old A loads  => vmcnt(4) at phase 2.
//   Symmetric schedule + s_barrier makes the per-wave guarantee collective.
// Tail: kt=31 re-stages tile 31 (identical bytes; preserves the ledger).
//
// Grid 384 (16M x 24N), XCD-chunked bijective swizzle: each XCD gets 3
// consecutive B-panels (2 MB, L2-fit) x 16 M-tiles.
// Reads/MFMA = 24/64 = 0.375 b128 — LDS pipe below matrix pipe.
// ===========================================================================
__global__ __launch_bounds__(512, 2) void gemm_qkv(const unsigned short* __restrict__ A,
                                                   const unsigned short* __restrict__ Bt,
                                                   unsigned short* __restrict__ Qo,
                                                   unsigned short* __restrict__ Ko,
                                                   unsigned short* __restrict__ Vo,
                                                   const float* __restrict__ cosp,
                                                   const float* __restrict__ sinp) {
    __shared__ unsigned short SM[65536];  // 128 KB: 2 x (A 16384 + B 16384) shorts
    int t = threadIdx.x;
    int w = t >> 6, lane = t & 63;
    int wm = w >> 2, wn = w & 3;          // 2 x 4 waves; wave out = 128 x 64
    int c = lane & 15, quad = lane >> 4;

    int bid = blockIdx.x;
    int wgid = (bid & 7) * 48 + (bid >> 3);   // XCD-chunked, bijective (384%8==0)
    int bx = wgid >> 4, by = wgid & 15;       // 24 N-panels x 16 M-tiles
    int m0 = by * 256, n0 = bx * 256;

    // staging: wave w, load j covers rows j*64 + w*8 + (lane>>3) of the matrix
    // panel; 16B chunk (lane&7)^((lane>>3)&7) (pre-swizzled source).
    int lr = lane >> 3;
    int cb = (lane & 7) ^ (lr & 7);
    const unsigned short* Agp = A  + (size_t)(m0 + w * 8 + lr) * HID + cb * 8;
    const unsigned short* Bgp = Bt + (size_t)(n0 + w * 8 + lr) * HID + cb * 8;

    f32x4 zero = {0.f, 0.f, 0.f, 0.f};
    f32x4 acc[8][4];
#pragma unroll
    for (int i = 0; i < 8; i++)
#pragma unroll
        for (int j = 0; j < 4; j++) acc[i][j] = zero;

    // ST(buf, MTX, J, KT): stage block-load J (64 rows) of matrix MTX, K-tile KT
#define ST(BUF, MTX, J, KT) async16(                                            \
        ((MTX) ? Bgp : Agp) + (KT) * 64 + (size_t)(J) * 64 * HID,               \
        SM + (BUF) * 32768 + (MTX) * 16384 + (J) * 4096 + w * 512)

    // prologue: stage tile 0 fully, drain, publish.
    ST(0, 1, 0, 0); ST(0, 1, 1, 0); ST(0, 1, 2, 0); ST(0, 1, 3, 0);
    ST(0, 0, 0, 0); ST(0, 0, 2, 0); ST(0, 0, 1, 0); ST(0, 0, 3, 0);
    __builtin_amdgcn_s_waitcnt(0x0F70);  // vmcnt(0)
    __builtin_amdgcn_s_barrier();

#pragma unroll 1
    for (int kt = 0; kt < 32; kt++) {
        const unsigned short* Ab = SM + (kt & 1) * 32768;
        const unsigned short* Bb = Ab + 16384;
        int ktn = kt + 1; if (ktn > 31) ktn = 31;   // tail: dup re-stage
        int nb = (kt + 1) & 1;                       // dest buf (dead at tail)
        bf16x8 bfr[4][2], af[2][2];

        // ---------- phase 1: B-frags (all) + A mt0,1; stage B J0,J1 ----------
#pragma unroll
        for (int nt = 0; nt < 4; nt++)
#pragma unroll
            for (int kk = 0; kk < 2; kk++)
                bfr[nt][kk] = *(const bf16x8*)(Bb + (wn * 64 + nt * 16 + c) * 64 +
                                               (((kk * 4 + quad) ^ (c & 7)) * 8));
#pragma unroll
        for (int mt = 0; mt < 2; mt++)
#pragma unroll
            for (int kk = 0; kk < 2; kk++)
                af[mt][kk] = *(const bf16x8*)(Ab + (wm * 128 + mt * 16 + c) * 64 +
                                              (((kk * 4 + quad) ^ (c & 7)) * 8));
        ST(nb, 1, 0, ktn); ST(nb, 1, 1, ktn);
        __builtin_amdgcn_s_barrier();
        __builtin_amdgcn_sched_barrier(0);
        __builtin_amdgcn_s_setprio(1);
#pragma unroll
        for (int mt = 0; mt < 2; mt++)
#pragma unroll
            for (int nt = 0; nt < 4; nt++)
#pragma unroll
                for (int kk = 0; kk < 2; kk++)
                    acc[mt][nt] = __builtin_amdgcn_mfma_f32_16x16x32_bf16(
                        af[mt][kk], bfr[nt][kk], acc[mt][nt], 0, 0, 0);
        __builtin_amdgcn_s_setprio(0);
        __builtin_amdgcn_s_barrier();

        // ---------- phase 2: A mt2,3; stage B J2,J3; vmcnt(4) drains old A J1,J3 ----------
#pragma unroll
        for (int mt = 0; mt < 2; mt++)
#pragma unroll
            for (int kk = 0; kk < 2; kk++)
                af[mt][kk] = *(const bf16x8*)(Ab + (wm * 128 + (mt + 2) * 16 + c) * 64 +
                                              (((kk * 4 + quad) ^ (c & 7)) * 8));
        ST(nb, 1, 2, ktn); ST(nb, 1, 3, ktn);
        __builtin_amdgcn_s_waitcnt(0x0F74);  // vmcnt(4): this tile's A J1,J3 landed
        __builtin_amdgcn_s_barrier();
        __builtin_amdgcn_sched_barrier(0);
        __builtin_amdgcn_s_setprio(1);
#pragma unroll
        for (int mt = 0; mt < 2; mt++)
#pragma unroll
            for (int nt = 0; nt < 4; nt++)
#pragma unroll
                for (int kk = 0; kk < 2; kk++)
                    acc[mt + 2][nt] = __builtin_amdgcn_mfma_f32_16x16x32_bf16(
                        af[mt][kk], bfr[nt][kk], acc[mt + 2][nt], 0, 0, 0);
        __builtin_amdgcn_s_setprio(0);
        __builtin_amdgcn_s_barrier();

        // ---------- phase 3: A mt4,5; stage A J0,J2 ----------
#pragma unroll
        for (int mt = 0; mt < 2; mt++)
#pragma unroll
            for (int kk = 0; kk < 2; kk++)
                af[mt][kk] = *(const bf16x8*)(Ab + (wm * 128 + (mt + 4) * 16 + c) * 64 +
                                              (((kk * 4 + quad) ^ (c & 7)) * 8));
        ST(nb, 0, 0, ktn); ST(nb, 0, 2, ktn);
        __builtin_amdgcn_s_barrier();
        __builtin_amdgcn_sched_barrier(0);
        __builtin_amdgcn_s_setprio(1);
#pragma unroll
        for (int mt = 0; mt < 2; mt++)
#pragma unroll
            for (int nt = 0; nt < 4; nt++)
#pragma unroll
                for (int kk = 0; kk < 2; kk++)
                    acc[mt + 4][nt] = __builtin_amdgcn_mfma_f32_16x16x32_bf16(
                        af[mt][kk], bfr[nt][kk], acc[mt + 4][nt], 0, 0, 0);
        __builtin_amdgcn_s_setprio(0);
        __builtin_amdgcn_s_barrier();

        // ---------- phase 4: A mt6,7; stage A J1,J3; vmcnt(2) -> publish ----------
#pragma unroll
        for (int mt = 0; mt < 2; mt++)
#pragma unroll
            for (int kk = 0; kk < 2; kk++)
                af[mt][kk] = *(const bf16x8*)(Ab + (wm * 128 + (mt + 6) * 16 + c) * 64 +
                                              (((kk * 4 + quad) ^ (c & 7)) * 8));
        ST(nb, 0, 1, ktn); ST(nb, 0, 3, ktn);
        __builtin_amdgcn_s_waitcnt(0x0F72);  // vmcnt(2): all next-ph1 data landed;
                                             // only A J1,J3 of kt+1 stay in flight
        __builtin_amdgcn_s_barrier();
        __builtin_amdgcn_sched_barrier(0);
        __builtin_amdgcn_s_setprio(1);
#pragma unroll
        for (int mt = 0; mt < 2; mt++)
#pragma unroll
            for (int nt = 0; nt < 4; nt++)
#pragma unroll
                for (int kk = 0; kk < 2; kk++)
                    acc[mt + 6][nt] = __builtin_amdgcn_mfma_f32_16x16x32_bf16(
                        af[mt][kk], bfr[nt][kk], acc[mt + 6][nt], 0, 0, 0);
        __builtin_amdgcn_s_setprio(0);
        __builtin_amdgcn_s_barrier();   // dbuf publish
    }
#undef ST

    __syncthreads();  // full drain (incl. tail dup DMA) before SM reuse

    // ---- epilogue (verified in r2): 32 slabs of 2048 shorts = 128 KB exact.
    // RoPE partner (col^64) = wave^1, same lane/(mt,nt,r). 256-col tile spans
    // 2 heads; h = hbase + (wn>>1).
    int mat = n0 >> 11;                 // block-uniform: 0=Q, 1=K, 2=V
    int hbase = (n0 & 2047) >> 7;
    int h = hbase + (wn >> 1);
    if (mat == 2) {
        // V^T: [b][h][d][s], 4 consecutive s per lane -> packed 8B store
#pragma unroll
        for (int mt = 0; mt < 8; mt++)
#pragma unroll
            for (int nt = 0; nt < 4; nt++) {
                int d = (wn & 1) * 64 + nt * 16 + c;
                int row0 = m0 + wm * 128 + mt * 16 + quad * 4;
                int b = row0 >> 11, s = row0 & 2047;
                ushort4 o;
                o.x = f2bf(acc[mt][nt][0]);
                o.y = f2bf(acc[mt][nt][1]);
                o.z = f2bf(acc[mt][nt][2]);
                o.w = f2bf(acc[mt][nt][3]);
                *(ushort4*)(Vo + ((size_t)(b * NH + h) * HD + d) * S_LEN + s) = o;
            }
    } else {
        unsigned short* Cb = (mat == 0) ? Qo : Ko;
        float scl = (mat == 0) ? 0.12751743f : 1.0f;  // log2(e)/sqrt(128) folded into Q
#pragma unroll
        for (int mt = 0; mt < 8; mt++)
#pragma unroll
            for (int nt = 0; nt < 4; nt++) {
                ushort4 o;
                o.x = f2bf(acc[mt][nt][0]);
                o.y = f2bf(acc[mt][nt][1]);
                o.z = f2bf(acc[mt][nt][2]);
                o.w = f2bf(acc[mt][nt][3]);
                *(ushort4*)(SM + (mt * 4 + nt) * 2048 + t * 4) = o;
            }
        __syncthreads();
        int partner = (w ^ 1) * 64 + lane;
        float sgn = (wn & 1) ? 1.0f : -1.0f;
#pragma unroll
        for (int mt = 0; mt < 8; mt++) {
#pragma unroll
            for (int nt = 0; nt < 4; nt++) {
                ushort4 pv = *(const ushort4*)(SM + (mt * 4 + nt) * 2048 + partner * 4);
                float part[4] = {bf2f(pv.x), bf2f(pv.y), bf2f(pv.z), bf2f(pv.w)};
                int d = (wn & 1) * 64 + nt * 16 + c;
#pragma unroll
                for (int r = 0; r < 4; r++) {
                    int row = m0 + wm * 128 + mt * 16 + quad * 4 + r;
                    int b = row >> 11, s = row & 2047;
                    float cv = cosp[s * HD + d], sv = sinp[s * HD + d];
                    float out = (acc[mt][nt][r] * cv + sgn * part[r] * sv) * scl;
                    Cb[((size_t)(b * NH + h) * S_LEN + s) * HD + d] = f2bf(out);
                }
            }
        }
    }
}

// ---------------- bf16 GEMM, BK=64 XOR-swizzled staging (legacy 128^2) ----------------
// Kept for the fallback path and for the output GEMM (MODE 2: 512 blocks).
template <int MODE>
__global__ __launch_bounds__(256, 2) void gemm_bt(const unsigned short* __restrict__ A,
                                                  const unsigned short* __restrict__ Bt,
                                                  unsigned short* __restrict__ Qo,
                                                  unsigned short* __restrict__ Ko,
                                                  unsigned short* __restrict__ Vo,
                                                  float* __restrict__ Fo,
                                                  const float* __restrict__ cosp,
                                                  const float* __restrict__ sinp,
                                                  int n_shift) {
    __shared__ unsigned short SM[16384];       // 32 KB: Asm(16K) + Bsm(16K); reused for rope swap
    unsigned short* Asm = SM;                  // 128 rows x 64 shorts, XOR-swizzled cols
    unsigned short* Bsm = SM + 8192;
    int t = threadIdx.x;
    int wave = t >> 6, lane = t & 63;
    int wm = wave >> 1, wn = wave & 1;
    int c = lane & 15, quad = lane >> 4;
    int m0 = blockIdx.y * 128, nloc = blockIdx.x * 128;

    int lr = lane >> 3;
    int cb = (lane & 7) ^ (lr & 7);
    const unsigned short* Ag = A + (size_t)(m0 + wave * 32 + lr) * HID + cb * 8;
    const unsigned short* Bg = Bt + (size_t)(nloc + wave * 32 + lr) * HID + cb * 8;
    unsigned short* Al = Asm + wave * 2048;  // 32 rows * 64 shorts
    unsigned short* Bl = Bsm + wave * 2048;

    f32x4 zero = {0.f, 0.f, 0.f, 0.f};
    f32x4 acc[4][4];
#pragma unroll
    for (int i = 0; i < 4; i++)
#pragma unroll
        for (int j = 0; j < 4; j++) acc[i][j] = zero;

    for (int it = 0; it < 32; it++) {
        int k0 = it * 64;
#pragma unroll
        for (int j = 0; j < 4; j++) {
            async16(Ag + k0 + j * 8 * HID, Al + j * 512);
            async16(Bg + k0 + j * 8 * HID, Bl + j * 512);
        }
        __syncthreads();
#pragma unroll
        for (int kk = 0; kk < 2; kk++) {
            bf16x8 af[4], bfr[4];
#pragma unroll
            for (int mt = 0; mt < 4; mt++)
                af[mt] = *(const bf16x8*)(Asm + (wm * 64 + mt * 16 + c) * 64 +
                                          (((kk * 4 + quad) ^ (c & 7)) * 8));
#pragma unroll
            for (int nt = 0; nt < 4; nt++)
                bfr[nt] = *(const bf16x8*)(Bsm + (wn * 64 + nt * 16 + c) * 64 +
                                           (((kk * 4 + quad) ^ (c & 7)) * 8));
#pragma unroll
            for (int mt = 0; mt < 4; mt++)
#pragma unroll
                for (int nt = 0; nt < 4; nt++)
                    acc[mt][nt] = __builtin_amdgcn_mfma_f32_16x16x32_bf16(af[mt], bfr[nt],
                                                                          acc[mt][nt], 0, 0, 0);
        }
        __syncthreads();
    }

    if (MODE == 2) {
#pragma unroll
        for (int mt = 0; mt < 4; mt++)
#pragma unroll
            for (int nt = 0; nt < 4; nt++)
#pragma unroll
                for (int r = 0; r < 4; r++) {
                    int row = m0 + wm * 64 + mt * 16 + quad * 4 + r;
                    int col = nloc + wn * 64 + nt * 16 + c;
                    Fo[(size_t)row * HID + col] = acc[mt][nt][r];
                }
    } else {
        int nglob0 = n_shift + nloc;
        int mat = nglob0 >> 11;         // block-uniform
        int h = (nglob0 & 2047) >> 7;   // block covers exactly one head (128 cols)
        if (mat == 2) {
#pragma unroll
            for (int mt = 0; mt < 4; mt++)
#pragma unroll
                for (int nt = 0; nt < 4; nt++) {
                    int d = wn * 64 + nt * 16 + c;
                    int row0 = m0 + wm * 64 + mt * 16 + quad * 4;
                    int b = row0 >> 11, s = row0 & 2047;
                    ushort4 o;
                    o.x = f2bf(acc[mt][nt][0]);
                    o.y = f2bf(acc[mt][nt][1]);
                    o.z = f2bf(acc[mt][nt][2]);
                    o.w = f2bf(acc[mt][nt][3]);
                    *(ushort4*)(Vo + ((size_t)(b * NH + h) * HD + d) * S_LEN + s) = o;
                }
        } else {
            unsigned short* Cb = (mat == 0) ? Qo : Ko;
            float scl = (mat == 0) ? 0.12751743f : 1.0f;
            __syncthreads();
#pragma unroll
            for (int mt = 0; mt < 4; mt++)
#pragma unroll
                for (int nt = 0; nt < 4; nt++) {
                    ushort4 o;
                    o.x = f2bf(acc[mt][nt][0]);
                    o.y = f2bf(acc[mt][nt][1]);
                    o.z = f2bf(acc[mt][nt][2]);
                    o.w = f2bf(acc[mt][nt][3]);
                    *(ushort4*)(SM + (mt * 4 + nt) * 1024 + t * 4) = o;
                }
            __syncthreads();
            int partner = (wm * 2 + (wn ^ 1)) * 64 + lane;
            float sgn = wn ? 1.0f : -1.0f;
#pragma unroll
            for (int mt = 0; mt < 4; mt++) {
#pragma unroll
                for (int nt = 0; nt < 4; nt++) {
                    ushort4 pv = *(const ushort4*)(SM + (mt * 4 + nt) * 1024 + partner * 4);
                    float part[4] = {bf2f(pv.x), bf2f(pv.y), bf2f(pv.z), bf2f(pv.w)};
                    int col = wn * 64 + nt * 16 + c;
#pragma unroll
                    for (int r = 0; r < 4; r++) {
                        int row = m0 + wm * 64 + mt * 16 + quad * 4 + r;
                        int b = row >> 11, s = row & 2047;
                        float cv = cosp[s * HD + col], sv = sinp[s * HD + col];
                        float out = (acc[mt][nt][r] * cv + sgn * part[r] * sv) * scl;
                        Cb[((size_t)(b * NH + h) * S_LEN + s) * HD + col] = f2bf(out);
                    }
                }
            }
        }
    }
}

// ---------------- flash attention (no-max online softmax, S^T formulation) ----------------
#define PKS 72  // P row stride in shorts (144B = 9*16: b128-aligned, conflict-free)
__global__ __launch_bounds__(256, 2) void attn_kernel(const unsigned short* __restrict__ Q,
                                                      const unsigned short* __restrict__ Kg,
                                                      const unsigned short* __restrict__ Vt,
                                                      unsigned short* __restrict__ Aout) {
    __shared__ unsigned short Ksm[64 * 128];            // 16 KB, [key][d], XOR-swizzled chunks
    __shared__ unsigned short Vsm[128 * 64];            // 16 KB, [d][key], XOR-swizzled chunks
    __shared__ __align__(16) unsigned short Psm[4 * 2 * 16 * PKS];  // 18 KB
    int bh = blockIdx.y;
    int b = bh >> 4, h = bh & 15;
    int t = threadIdx.x;
    int wave = t >> 6, lane = t & 63;
    int c = lane & 15, quad = lane >> 4;
    int q0 = blockIdx.x * 128 + wave * 32;
    const unsigned short* Qp = Q + (size_t)bh * S_LEN * HD;
    const unsigned short* Kp = Kg + (size_t)bh * S_LEN * HD;
    const unsigned short* Vp = Vt + (size_t)bh * HD * S_LEN;

    bf16x8 qf[2][4];
#pragma unroll
    for (int qn = 0; qn < 2; qn++)
#pragma unroll
        for (int kk = 0; kk < 4; kk++)
            qf[qn][kk] = *(const bf16x8*)(Qp + (size_t)(q0 + qn * 16 + c) * HD + kk * 32 + quad * 8);

    f32x4 zero = {0.f, 0.f, 0.f, 0.f};
    f32x4 o_acc[2][8];
#pragma unroll
    for (int qn = 0; qn < 2; qn++)
#pragma unroll
        for (int nt = 0; nt < 8; nt++) o_acc[qn][nt] = zero;
    float lsum[2] = {0.f, 0.f};

    for (int key0 = 0; key0 < S_LEN; key0 += 64) {
#pragma unroll
        for (int j = 0; j < 4; j++) {
            int fc = (wave * 4 + j) * 64 + lane;
            int rK = fc >> 4, cbK = (fc & 15) ^ (rK & 15);
            async16(Kp + (size_t)(key0 + rK) * HD + cbK * 8, Ksm + (wave * 4 + j) * 512);
            int rV = fc >> 3, cbV = (fc & 7) ^ (rV & 7);
            async16(Vp + (size_t)rV * S_LEN + key0 + cbV * 8, Vsm + (wave * 4 + j) * 512);
        }
        __syncthreads();

        f32x4 sacc[4][2];
#pragma unroll
        for (int km = 0; km < 4; km++)
#pragma unroll
            for (int qn = 0; qn < 2; qn++) sacc[km][qn] = zero;
#pragma unroll
        for (int kk = 0; kk < 4; kk++) {
            bf16x8 kfr[4];
#pragma unroll
            for (int km = 0; km < 4; km++)
                kfr[km] = *(const bf16x8*)(Ksm + (km * 16 + c) * HD + (((kk * 4 + quad) ^ c)) * 8);
#pragma unroll
            for (int km = 0; km < 4; km++)
#pragma unroll
                for (int qn = 0; qn < 2; qn++)
                    sacc[km][qn] = __builtin_amdgcn_mfma_f32_16x16x32_bf16(kfr[km], qf[qn][kk],
                                                                           sacc[km][qn], 0, 0, 0);
        }

#pragma unroll
        for (int qn = 0; qn < 2; qn++) {
#pragma unroll
            for (int km = 0; km < 4; km++) {
                float e0 = exp2_fast(sacc[km][qn][0]);
                float e1 = exp2_fast(sacc[km][qn][1]);
                float e2 = exp2_fast(sacc[km][qn][2]);
                float e3 = exp2_fast(sacc[km][qn][3]);
                lsum[qn] += (e0 + e1) + (e2 + e3);
                uint2 pk;
                pk.x = pkbf(e0, e1);
                pk.y = pkbf(e2, e3);
                *(uint2*)(Psm + ((wave * 2 + qn) * 16 + c) * PKS + km * 16 + quad * 4) = pk;
            }
        }
        asm volatile("" ::: "memory");
        __builtin_amdgcn_s_waitcnt(0xc07f);  // lgkmcnt(0), vmcnt/expcnt unaffected
        asm volatile("" ::: "memory");

#pragma unroll
        for (int kf = 0; kf < 2; kf++) {
            bf16x8 pf[2];
#pragma unroll
            for (int qn = 0; qn < 2; qn++)
                pf[qn] = *(const bf16x8*)(Psm + ((wave * 2 + qn) * 16 + c) * PKS + kf * 32 + quad * 8);
#pragma unroll
            for (int nt = 0; nt < 8; nt++) {
                bf16x8 vf = *(const bf16x8*)(Vsm + (nt * 16 + c) * 64 +
                                             (((kf * 4 + quad) ^ (c & 7))) * 8);
#pragma unroll
                for (int qn = 0; qn < 2; qn++)
                    o_acc[qn][nt] = __builtin_amdgcn_mfma_f32_16x16x32_bf16(pf[qn], vf,
                                                                            o_acc[qn][nt], 0, 0, 0);
            }
        }
        __syncthreads();
    }

#pragma unroll
    for (int qn = 0; qn < 2; qn++) {
        lsum[qn] += __shfl_xor(lsum[qn], 16);
        lsum[qn] += __shfl_xor(lsum[qn], 32);
    }
    float inv[2][4];
#pragma unroll
    for (int qn = 0; qn < 2; qn++)
#pragma unroll
        for (int r = 0; r < 4; r++)
            inv[qn][r] = 1.0f / __shfl(lsum[qn], quad * 4 + r);

#pragma unroll
    for (int qn = 0; qn < 2; qn++) {
#pragma unroll
        for (int r = 0; r < 4; r++) {
            int srow = q0 + qn * 16 + quad * 4 + r;
            size_t base = ((size_t)(b * S_LEN + srow)) * HID + h * HD;
#pragma unroll
            for (int nt = 0; nt < 8; nt++)
                Aout[base + nt * 16 + c] = f2bf(o_acc[qn][nt][r] * inv[qn][r]);
        }
    }
}

extern "C" void kernel_launch(void* const* d_in, const int* in_sizes, int n_in,
                              void* d_out, int out_size, void* d_ws, size_t ws_size,
                              hipStream_t stream) {
    const float* hs   = (const float*)d_in[0];
    const float* cosp = (const float*)d_in[1];
    const float* sinp = (const float*)d_in[2];
    const float* Wq   = (const float*)d_in[3];
    const float* Wk   = (const float*)d_in[4];
    const float* Wv   = (const float*)d_in[5];
    const float* Wo   = (const float*)d_in[6];

    char* ws = (char*)d_ws;
    unsigned short* Xb = (unsigned short*)(ws);                      // 0-16 MB (reused as Aout)
    unsigned short* Qb = (unsigned short*)(ws + (16ull << 20));      // 16-32
    unsigned short* Kb = (unsigned short*)(ws + (32ull << 20));      // 32-48
    unsigned short* Vb = (unsigned short*)(ws + (48ull << 20));      // 48-64
    unsigned short* WT = (unsigned short*)(ws + (64ull << 20));      // 64-88 fused / 64-72 single

    const bool fused = ws_size >= (88ull << 20);

    if (fused) {
        // 1. cast + 3 weight transposes in one launch
        prep<<<dim3(64, 64, 4), 256, 0, stream>>>(hs, Wq, Wk, Wv, Xb, WT);
        // 2. fused QKV GEMM (256^2 4-phase template, fixed vmcnt ledger) + RoPE
        gemm_qkv<<<dim3(384), 512, 0, stream>>>(Xb, WT, Qb, Kb, Vb, cosp, sinp);
        // 3. flash attention
        attn_kernel<<<dim3(16, 32), 256, 0, stream>>>(Qb, Kb, Vb, Xb /*Aout*/);
        // 4. Wo transpose into dead Qb region
        unsigned short* WoT = (unsigned short*)(ws + (16ull << 20));
        transpose_cast<<<dim3(64, 64), 256, 0, stream>>>(Wo, WoT);
        // 5. output GEMM, fp32 direct to d_out
        gemm_bt<2><<<dim3(16, 32), 256, 0, stream>>>(Xb, WoT, nullptr, nullptr, nullptr,
                                                     (float*)d_out, cosp, sinp, 0);
    } else {
        prep<<<dim3(64, 64, 1), 256, 0, stream>>>(hs, Wq, Wq, Wq, Xb, WT);
        prep<<<dim3(64, 64, 4), 256, 0, stream>>>(hs, Wq, Wq, Wq, Xb, WT);  // cast + Wq^T
        gemm_bt<0><<<dim3(16, 32), 256, 0, stream>>>(Xb, WT, Qb, Kb, Vb, nullptr,
                                                     cosp, sinp, 0);
        transpose_cast<<<dim3(64, 64), 256, 0, stream>>>(Wk, WT);
        gemm_bt<0><<<dim3(16, 32), 256, 0, stream>>>(Xb, WT, Qb, Kb, Vb, nullptr,
                                                     cosp, sinp, 2048);
        transpose_cast<<<dim3(64, 64), 256, 0, stream>>>(Wv, WT);
        gemm_bt<0><<<dim3(16, 32), 256, 0, stream>>>(Xb, WT, Qb, Kb, Vb, nullptr,
                                                     cosp, sinp, 4096);
        attn_kernel<<<dim3(16, 32), 256, 0, stream>>>(Qb, Kb, Vb, Xb /*Aout*/);
        transpose_cast<<<dim3(64, 64), 256, 0, stream>>>(Wo, WT);
        gemm_bt<2><<<dim3(16, 32), 256, 0, stream>>>(Xb, WT, nullptr, nullptr, nullptr,
                                                     (float*)d_out, cosp, sinp, 0);
    }
}

// Round 7
// 387.806 us; speedup vs baseline: 1.2208x; 1.2208x over previous
//
#include <hip/hip_runtime.h>

typedef short bf16x8 __attribute__((ext_vector_type(8)));
typedef float f32x4 __attribute__((ext_vector_type(4)));

#define HID   2048
#define S_LEN 2048
#define NH    16
#define HD    128
#define BATCH 2
#define NROWS (BATCH * S_LEN)  // 4096

__device__ __forceinline__ float bf2f(unsigned short u) {
    union { unsigned int i; float f; } v;
    v.i = ((unsigned int)u) << 16;
    return v.f;
}
__device__ __forceinline__ unsigned short f2bf(float f) {
    union { float f; unsigned int i; } v;
    v.f = f;
    unsigned int u = v.i;
    return (unsigned short)((u + 0x7fffu + ((u >> 16) & 1u)) >> 16);
}

// packed f32x2 -> bf16x2 (RNE). Prefer HW v_cvt_pk_bf16_f32 on gfx950.
__device__ __forceinline__ unsigned int pkbf(float a, float b) {
#if defined(__has_builtin) && __has_builtin(__builtin_amdgcn_cvt_pk_bf16_f32)
    typedef __bf16 bf2_t __attribute__((ext_vector_type(2)));
    bf2_t v = __builtin_amdgcn_cvt_pk_bf16_f32(a, b);
    unsigned int u;
    __builtin_memcpy(&u, &v, 4);
    return u;
#else
    return (unsigned int)f2bf(a) | ((unsigned int)f2bf(b) << 16);
#endif
}

__device__ __forceinline__ float exp2_fast(float x) {
#if defined(__has_builtin) && __has_builtin(__builtin_amdgcn_exp2f)
    return __builtin_amdgcn_exp2f(x);
#else
    return __expf(x * 0.6931471805599453f);
#endif
}

// async global->LDS, 16B per lane. LDS dest = wave-uniform base + lane*16B.
__device__ __forceinline__ void async16(const unsigned short* g, unsigned short* l) {
    __builtin_amdgcn_global_load_lds(
        (const __attribute__((address_space(1))) unsigned int*)g,
        (__attribute__((address_space(3))) unsigned int*)l, 16, 0, 0);
}

// ---------------- prep: z<3 -> transpose+cast W_z; z==3 -> cast hs -> bf16 ----------------
__global__ __launch_bounds__(256) void prep(const float* __restrict__ hs,
                                            const float* __restrict__ Wa,
                                            const float* __restrict__ Wb,
                                            const float* __restrict__ Wc,
                                            unsigned short* __restrict__ Xb,
                                            unsigned short* __restrict__ WT) {
    int z = blockIdx.z;
    int t = threadIdx.x;
    if (z == 3) {
        size_t idx = (((size_t)blockIdx.y * 64 + blockIdx.x) * 256 + t) * 8;
        float4 v0 = *(const float4*)(hs + idx);
        float4 v1 = *(const float4*)(hs + idx + 4);
        uint4 o;
        o.x = pkbf(v0.x, v0.y);
        o.y = pkbf(v0.z, v0.w);
        o.z = pkbf(v1.x, v1.y);
        o.w = pkbf(v1.z, v1.w);
        *(uint4*)(Xb + idx) = o;
        return;
    }
    __shared__ float tile[32][33];
    int tx = t & 31, ty = t >> 5;  // 32 x 8
    int bx = blockIdx.x, by = blockIdx.y;
    const float* W = (z == 0) ? Wa : ((z == 1) ? Wb : Wc);
    unsigned short* dst = WT + (size_t)z * HID * HID;
#pragma unroll
    for (int i = 0; i < 4; i++)
        tile[ty + i * 8][tx] = W[(size_t)(by * 32 + ty + i * 8) * HID + bx * 32 + tx];
    __syncthreads();
#pragma unroll
    for (int i = 0; i < 4; i++)
        dst[(size_t)(bx * 32 + ty + i * 8) * HID + by * 32 + tx] = f2bf(tile[tx][ty + i * 8]);
}

// ---------------- standalone transpose + cast (used for Wo) ----------------
__global__ __launch_bounds__(256) void transpose_cast(const float* __restrict__ W,
                                                      unsigned short* __restrict__ WT) {
    __shared__ float tile[32][33];
    int t = threadIdx.x;
    int tx = t & 31, ty = t >> 5;
    int bx = blockIdx.x, by = blockIdx.y;
#pragma unroll
    for (int i = 0; i < 4; i++)
        tile[ty + i * 8][tx] = W[(size_t)(by * 32 + ty + i * 8) * HID + bx * 32 + tx];
    __syncthreads();
#pragma unroll
    for (int i = 0; i < 4; i++)
        WT[(size_t)(bx * 32 + ty + i * 8) * HID + by * 32 + tx] = f2bf(tile[tx][ty + i * 8]);
}

// ---------------- bf16 GEMM, BK=64 XOR-swizzled staging (proven 128^2) ----------------
// The r0 kernel: 121.8 us / 846 TF / 37% MfmaUtil / 0 bank conflicts on the
// QKV shape. Four pipeline rewrites (r2-r6) all measured slower; reverted.
// MODE 0: mat = nglob>>11: 0 -> Qo (rope, *log2e/sqrt(D)), 1 -> Ko (rope);
//         2 -> Vo [b][h][d][s] (transposed, packed stores)
// MODE 2: write fp32 to Fo[row][col]
template <int MODE>
__global__ __launch_bounds__(256, 2) void gemm_bt(const unsigned short* __restrict__ A,
                                                  const unsigned short* __restrict__ Bt,
                                                  unsigned short* __restrict__ Qo,
                                                  unsigned short* __restrict__ Ko,
                                                  unsigned short* __restrict__ Vo,
                                                  float* __restrict__ Fo,
                                                  const float* __restrict__ cosp,
                                                  const float* __restrict__ sinp,
                                                  int n_shift) {
    __shared__ unsigned short SM[16384];       // 32 KB: Asm(16K) + Bsm(16K); reused for rope swap
    unsigned short* Asm = SM;                  // 128 rows x 64 shorts, XOR-swizzled cols
    unsigned short* Bsm = SM + 8192;
    int t = threadIdx.x;
    int wave = t >> 6, lane = t & 63;
    int wm = wave >> 1, wn = wave & 1;
    int c = lane & 15, quad = lane >> 4;
    int m0 = blockIdx.y * 128, nloc = blockIdx.x * 128;

    int lr = lane >> 3;
    int cb = (lane & 7) ^ (lr & 7);
    const unsigned short* Ag = A + (size_t)(m0 + wave * 32 + lr) * HID + cb * 8;
    const unsigned short* Bg = Bt + (size_t)(nloc + wave * 32 + lr) * HID + cb * 8;
    unsigned short* Al = Asm + wave * 2048;  // 32 rows * 64 shorts
    unsigned short* Bl = Bsm + wave * 2048;

    f32x4 zero = {0.f, 0.f, 0.f, 0.f};
    f32x4 acc[4][4];
#pragma unroll
    for (int i = 0; i < 4; i++)
#pragma unroll
        for (int j = 0; j < 4; j++) acc[i][j] = zero;

    for (int it = 0; it < 32; it++) {
        int k0 = it * 64;
#pragma unroll
        for (int j = 0; j < 4; j++) {
            async16(Ag + k0 + j * 8 * HID, Al + j * 512);
            async16(Bg + k0 + j * 8 * HID, Bl + j * 512);
        }
        __syncthreads();
#pragma unroll
        for (int kk = 0; kk < 2; kk++) {
            bf16x8 af[4], bfr[4];
#pragma unroll
            for (int mt = 0; mt < 4; mt++)
                af[mt] = *(const bf16x8*)(Asm + (wm * 64 + mt * 16 + c) * 64 +
                                          (((kk * 4 + quad) ^ (c & 7)) * 8));
#pragma unroll
            for (int nt = 0; nt < 4; nt++)
                bfr[nt] = *(const bf16x8*)(Bsm + (wn * 64 + nt * 16 + c) * 64 +
                                           (((kk * 4 + quad) ^ (c & 7)) * 8));
#pragma unroll
            for (int mt = 0; mt < 4; mt++)
#pragma unroll
                for (int nt = 0; nt < 4; nt++)
                    acc[mt][nt] = __builtin_amdgcn_mfma_f32_16x16x32_bf16(af[mt], bfr[nt],
                                                                          acc[mt][nt], 0, 0, 0);
        }
        __syncthreads();
    }

    if (MODE == 2) {
#pragma unroll
        for (int mt = 0; mt < 4; mt++)
#pragma unroll
            for (int nt = 0; nt < 4; nt++)
#pragma unroll
                for (int r = 0; r < 4; r++) {
                    int row = m0 + wm * 64 + mt * 16 + quad * 4 + r;
                    int col = nloc + wn * 64 + nt * 16 + c;
                    Fo[(size_t)row * HID + col] = acc[mt][nt][r];
                }
    } else {
        int nglob0 = n_shift + nloc;
        int mat = nglob0 >> 11;         // block-uniform
        int h = (nglob0 & 2047) >> 7;   // block covers exactly one head (128 cols)
        if (mat == 2) {
#pragma unroll
            for (int mt = 0; mt < 4; mt++)
#pragma unroll
                for (int nt = 0; nt < 4; nt++) {
                    int d = wn * 64 + nt * 16 + c;
                    int row0 = m0 + wm * 64 + mt * 16 + quad * 4;
                    int b = row0 >> 11, s = row0 & 2047;
                    ushort4 o;
                    o.x = f2bf(acc[mt][nt][0]);
                    o.y = f2bf(acc[mt][nt][1]);
                    o.z = f2bf(acc[mt][nt][2]);
                    o.w = f2bf(acc[mt][nt][3]);
                    *(ushort4*)(Vo + ((size_t)(b * NH + h) * HD + d) * S_LEN + s) = o;
                }
        } else {
            unsigned short* Cb = (mat == 0) ? Qo : Ko;
            float scl = (mat == 0) ? 0.12751743f : 1.0f;  // log2(e)/sqrt(128) folded into Q
            __syncthreads();
#pragma unroll
            for (int mt = 0; mt < 4; mt++)
#pragma unroll
                for (int nt = 0; nt < 4; nt++) {
                    ushort4 o;
                    o.x = f2bf(acc[mt][nt][0]);
                    o.y = f2bf(acc[mt][nt][1]);
                    o.z = f2bf(acc[mt][nt][2]);
                    o.w = f2bf(acc[mt][nt][3]);
                    *(ushort4*)(SM + (mt * 4 + nt) * 1024 + t * 4) = o;
                }
            __syncthreads();
            int partner = (wm * 2 + (wn ^ 1)) * 64 + lane;
            float sgn = wn ? 1.0f : -1.0f;
#pragma unroll
            for (int mt = 0; mt < 4; mt++) {
#pragma unroll
                for (int nt = 0; nt < 4; nt++) {
                    ushort4 pv = *(const ushort4*)(SM + (mt * 4 + nt) * 1024 + partner * 4);
                    float part[4] = {bf2f(pv.x), bf2f(pv.y), bf2f(pv.z), bf2f(pv.w)};
                    int col = wn * 64 + nt * 16 + c;
#pragma unroll
                    for (int r = 0; r < 4; r++) {
                        int row = m0 + wm * 64 + mt * 16 + quad * 4 + r;
                        int b = row >> 11, s = row & 2047;
                        float cv = cosp[s * HD + col], sv = sinp[s * HD + col];
                        float out = (acc[mt][nt][r] * cv + sgn * part[r] * sv) * scl;
                        Cb[((size_t)(b * NH + h) * S_LEN + s) * HD + col] = f2bf(out);
                    }
                }
            }
        }
    }
}

// ---------------- flash attention (no-max online softmax, S^T formulation) ----------------
// r7: counted-vmcnt async staging replaces the per-iteration __syncthreads
// (which drains vmcnt(0) and exposed the full DMA latency 32x per block).
// K double-buffered (2x16KB), V single-buffered; both staged at iteration END
// (after the post-PV barrier), order V(i+1) then K(i+2).
//
// Steady-state vmcnt ledger (issue order: ..., V(i) then K(i+1) at end of
// iter i-1, V(i+1) then K(i+2) at end of iter i, ...):
//   B0 (iter top):  outstanding {K(i),V(i),K(i+1)} = 12 -> vmcnt(8) drains
//                   exactly K(i) (oldest 4). QK^T reads Kbuf(i&1) safely.
//   B1 (pre-PV):    outstanding {V(i),K(i+1)} = 8 -> vmcnt(4) drains exactly
//                   V(i) (oldest 4); K(i+1) stays in flight across barriers.
//   B2 (post-PV):   plain barrier; all waves' Vsm/Kbuf reads complete, then
//                   stage into them.
// Prologue K0,V0,K1 reproduces the ledger (Q-frag loads issue first; B0's
// vmcnt(8) drains them too on iter 0). Tail: clamped re-stage of chunk 31
// (identical bytes) preserves the in-flight counts. sched_barrier(0) pins
// program order at every barrier (rule 18).
#define PKS 72  // P row stride in shorts (144B = 9*16: b128-aligned, conflict-free)
__global__ __launch_bounds__(256, 2) void attn_kernel(const unsigned short* __restrict__ Q,
                                                      const unsigned short* __restrict__ Kg,
                                                      const unsigned short* __restrict__ Vt,
                                                      unsigned short* __restrict__ Aout) {
    __shared__ unsigned short Ksm[2 * 64 * 128];        // 32 KB dbuf, [key][d], XOR-swizzled
    __shared__ unsigned short Vsm[128 * 64];            // 16 KB, [d][key], XOR-swizzled
    __shared__ __align__(16) unsigned short Psm[4 * 2 * 16 * PKS];  // 18 KB
    // total 66 KB -> 2 blocks/CU preserved
    int bh = blockIdx.y;
    int b = bh >> 4, h = bh & 15;
    int t = threadIdx.x;
    int wave = t >> 6, lane = t & 63;
    int c = lane & 15, quad = lane >> 4;
    int q0 = blockIdx.x * 128 + wave * 32;
    const unsigned short* Qp = Q + (size_t)bh * S_LEN * HD;
    const unsigned short* Kp = Kg + (size_t)bh * S_LEN * HD;
    const unsigned short* Vp = Vt + (size_t)bh * HD * S_LEN;

    // persistent Q fragments (issued first; drained by iter-0's B0 vmcnt)
    bf16x8 qf[2][4];
#pragma unroll
    for (int qn = 0; qn < 2; qn++)
#pragma unroll
        for (int kk = 0; kk < 4; kk++)
            qf[qn][kk] = *(const bf16x8*)(Qp + (size_t)(q0 + qn * 16 + c) * HD + kk * 32 + quad * 8);

    f32x4 zero = {0.f, 0.f, 0.f, 0.f};
    f32x4 o_acc[2][8];
#pragma unroll
    for (int qn = 0; qn < 2; qn++)
#pragma unroll
        for (int nt = 0; nt < 8; nt++) o_acc[qn][nt] = zero;
    float lsum[2] = {0.f, 0.f};

#define STAGE_K(CH, BUF) {                                                      \
    _Pragma("unroll")                                                           \
    for (int j = 0; j < 4; j++) {                                               \
        int fc = (wave * 4 + j) * 64 + lane;                                    \
        int rK = fc >> 4, cbK = (fc & 15) ^ (rK & 15);                          \
        async16(Kp + (size_t)((CH) * 64 + rK) * HD + cbK * 8,                   \
                Ksm + (BUF) * 8192 + (wave * 4 + j) * 512); } }
#define STAGE_V(CH) {                                                           \
    _Pragma("unroll")                                                           \
    for (int j = 0; j < 4; j++) {                                               \
        int fc = (wave * 4 + j) * 64 + lane;                                    \
        int rV = fc >> 3, cbV = (fc & 7) ^ (rV & 7);                            \
        async16(Vp + (size_t)rV * S_LEN + (CH) * 64 + cbV * 8,                  \
                Vsm + (wave * 4 + j) * 512); } }

    // prologue: ledger-consistent with steady state
    STAGE_K(0, 0);
    STAGE_V(0);
    STAGE_K(1, 1);

    for (int i = 0; i < 32; i++) {
        const unsigned short* Kb = Ksm + (i & 1) * 8192;
        __builtin_amdgcn_s_waitcnt(0x0F78);  // vmcnt(8): K(i) landed (+Q on i==0)
        __builtin_amdgcn_s_barrier();        // B0
        __builtin_amdgcn_sched_barrier(0);

        // S^T = K * Q^T : M=key (4 tiles), N=qrow (2 tiles), K=d (4 frags)
        f32x4 sacc[4][2];
#pragma unroll
        for (int km = 0; km < 4; km++)
#pragma unroll
            for (int qn = 0; qn < 2; qn++) sacc[km][qn] = zero;
#pragma unroll
        for (int kk = 0; kk < 4; kk++) {
            bf16x8 kfr[4];
#pragma unroll
            for (int km = 0; km < 4; km++)
                kfr[km] = *(const bf16x8*)(Kb + (km * 16 + c) * HD + (((kk * 4 + quad) ^ c)) * 8);
#pragma unroll
            for (int km = 0; km < 4; km++)
#pragma unroll
                for (int qn = 0; qn < 2; qn++)
                    sacc[km][qn] = __builtin_amdgcn_mfma_f32_16x16x32_bf16(kfr[km], qf[qn][kk],
                                                                           sacc[km][qn], 0, 0, 0);
        }

        // exp2 (scale pre-folded, no max subtraction), row-sum partials, pack P -> LDS
#pragma unroll
        for (int qn = 0; qn < 2; qn++) {
#pragma unroll
            for (int km = 0; km < 4; km++) {
                float e0 = exp2_fast(sacc[km][qn][0]);
                float e1 = exp2_fast(sacc[km][qn][1]);
                float e2 = exp2_fast(sacc[km][qn][2]);
                float e3 = exp2_fast(sacc[km][qn][3]);
                lsum[qn] += (e0 + e1) + (e2 + e3);
                uint2 pk;
                pk.x = pkbf(e0, e1);
                pk.y = pkbf(e2, e3);
                *(uint2*)(Psm + ((wave * 2 + qn) * 16 + c) * PKS + km * 16 + quad * 4) = pk;
            }
        }
        // intra-wave LDS write->read ordering: compiler fence + lgkmcnt(0)
        asm volatile("" ::: "memory");
        __builtin_amdgcn_s_waitcnt(0xc07f);  // lgkmcnt(0) only
        asm volatile("" ::: "memory");

        __builtin_amdgcn_sched_barrier(0);
        __builtin_amdgcn_s_waitcnt(0x0F74);  // vmcnt(4): V(i) landed; K(i+1) in flight
        __builtin_amdgcn_s_barrier();        // B1
        __builtin_amdgcn_sched_barrier(0);

        // O += P * V : A=P [qrow][key], B=Vt [d][key]
#pragma unroll
        for (int kf = 0; kf < 2; kf++) {
            bf16x8 pf[2];
#pragma unroll
            for (int qn = 0; qn < 2; qn++)
                pf[qn] = *(const bf16x8*)(Psm + ((wave * 2 + qn) * 16 + c) * PKS + kf * 32 + quad * 8);
#pragma unroll
            for (int nt = 0; nt < 8; nt++) {
                bf16x8 vf = *(const bf16x8*)(Vsm + (nt * 16 + c) * 64 +
                                             (((kf * 4 + quad) ^ (c & 7))) * 8);
#pragma unroll
                for (int qn = 0; qn < 2; qn++)
                    o_acc[qn][nt] = __builtin_amdgcn_mfma_f32_16x16x32_bf16(pf[qn], vf,
                                                                            o_acc[qn][nt], 0, 0, 0);
            }
        }
        __builtin_amdgcn_sched_barrier(0);
        __builtin_amdgcn_s_barrier();        // B2: all Vsm/Kbuf reads complete
        __builtin_amdgcn_sched_barrier(0);

        // stage next chunks (order matters for the ledger: V first, then K)
        int nv = (i + 1 > 31) ? 31 : i + 1;
        int nk = (i + 2 > 31) ? 31 : i + 2;
        STAGE_V(nv);
        STAGE_K(nk, (i & 1));
    }
#undef STAGE_K
#undef STAGE_V

    // final: reduce lsum over the 4 quad-lanes (row = c), broadcast to C-layout rows
#pragma unroll
    for (int qn = 0; qn < 2; qn++) {
        lsum[qn] += __shfl_xor(lsum[qn], 16);
        lsum[qn] += __shfl_xor(lsum[qn], 32);
    }
    float inv[2][4];
#pragma unroll
    for (int qn = 0; qn < 2; qn++)
#pragma unroll
        for (int r = 0; r < 4; r++)
            inv[qn][r] = 1.0f / __shfl(lsum[qn], quad * 4 + r);

#pragma unroll
    for (int qn = 0; qn < 2; qn++) {
#pragma unroll
        for (int r = 0; r < 4; r++) {
            int srow = q0 + qn * 16 + quad * 4 + r;
            size_t base = ((size_t)(b * S_LEN + srow)) * HID + h * HD;
#pragma unroll
            for (int nt = 0; nt < 8; nt++)
                Aout[base + nt * 16 + c] = f2bf(o_acc[qn][nt][r] * inv[qn][r]);
        }
    }
}

extern "C" void kernel_launch(void* const* d_in, const int* in_sizes, int n_in,
                              void* d_out, int out_size, void* d_ws, size_t ws_size,
                              hipStream_t stream) {
    const float* hs   = (const float*)d_in[0];
    const float* cosp = (const float*)d_in[1];
    const float* sinp = (const float*)d_in[2];
    const float* Wq   = (const float*)d_in[3];
    const float* Wk   = (const float*)d_in[4];
    const float* Wv   = (const float*)d_in[5];
    const float* Wo   = (const float*)d_in[6];

    char* ws = (char*)d_ws;
    unsigned short* Xb = (unsigned short*)(ws);                      // 0-16 MB (reused as Aout)
    unsigned short* Qb = (unsigned short*)(ws + (16ull << 20));      // 16-32
    unsigned short* Kb = (unsigned short*)(ws + (32ull << 20));      // 32-48
    unsigned short* Vb = (unsigned short*)(ws + (48ull << 20));      // 48-64
    unsigned short* WT = (unsigned short*)(ws + (64ull << 20));      // 64-88 fused / 64-72 single

    const bool fused = ws_size >= (88ull << 20);

    if (fused) {
        // 1. cast + 3 weight transposes in one launch
        prep<<<dim3(64, 64, 4), 256, 0, stream>>>(hs, Wq, Wk, Wv, Xb, WT);
        // 2. fused QKV GEMM with RoPE epilogue (proven r0 kernel, 846 TF)
        gemm_bt<0><<<dim3(48, 32), 256, 0, stream>>>(Xb, WT, Qb, Kb, Vb, nullptr,
                                                     cosp, sinp, 0);
        // 3. flash attention (async counted-vmcnt staging)
        attn_kernel<<<dim3(16, 32), 256, 0, stream>>>(Qb, Kb, Vb, Xb /*Aout*/);
        // 4. Wo transpose into dead Qb region
        unsigned short* WoT = (unsigned short*)(ws + (16ull << 20));
        transpose_cast<<<dim3(64, 64), 256, 0, stream>>>(Wo, WoT);
        // 5. output GEMM, fp32 direct to d_out
        gemm_bt<2><<<dim3(16, 32), 256, 0, stream>>>(Xb, WoT, nullptr, nullptr, nullptr,
                                                     (float*)d_out, cosp, sinp, 0);
    } else {
        prep<<<dim3(64, 64, 1), 256, 0, stream>>>(hs, Wq, Wq, Wq, Xb, WT);
        prep<<<dim3(64, 64, 4), 256, 0, stream>>>(hs, Wq, Wq, Wq, Xb, WT);  // cast + Wq^T
        gemm_bt<0><<<dim3(16, 32), 256, 0, stream>>>(Xb, WT, Qb, Kb, Vb, nullptr,
                                                     cosp, sinp, 0);
        transpose_cast<<<dim3(64, 64), 256, 0, stream>>>(Wk, WT);
        gemm_bt<0><<<dim3(16, 32), 256, 0, stream>>>(Xb, WT, Qb, Kb, Vb, nullptr,
                                                     cosp, sinp, 2048);
        transpose_cast<<<dim3(64, 64), 256, 0, stream>>>(Wv, WT);
        gemm_bt<0><<<dim3(16, 32), 256, 0, stream>>>(Xb, WT, Qb, Kb, Vb, nullptr,
                                                     cosp, sinp, 4096);
        attn_kernel<<<dim3(16, 32), 256, 0, stream>>>(Qb, Kb, Vb, Xb /*Aout*/);
        transpose_cast<<<dim3(64, 64), 256, 0, stream>>>(Wo, WT);
        gemm_bt<2><<<dim3(16, 32), 256, 0, stream>>>(Xb, WT, nullptr, nullptr, nullptr,
                                                     (float*)d_out, cosp, sinp, 0);
    }
}